// Round 1
// baseline (11343.761 us; speedup 1.0000x reference)
//
#include <hip/hip_runtime.h>
#include <hip/hip_bf16.h>
#include <hip/hip_cooperative_groups.h>

namespace cg = cooperative_groups;

#define SEQ   512
#define BATCH 64
#define INF   512
#define H     1024
#define G4H   4096

#define NBLK   128          // persistent blocks (<= 256 CUs, 1/CU)
#define NCOL   8            // hidden columns per block
#define WROWS  32           // 4 gates * NCOL weight rows per block
#define WPITCH 1544         // 1536 + 8 bf16 pad (rows 16B-aligned, banks spread)

typedef short  short8  __attribute__((ext_vector_type(8)));
typedef float  float4v __attribute__((ext_vector_type(4)));

// ---------------- conversion / init kernels ----------------

__global__ void f32_to_bf16_k(const float* __restrict__ src,
                              __hip_bfloat16* __restrict__ dst, int n) {
    int i = blockIdx.x * blockDim.x + threadIdx.x;
    int stride = gridDim.x * blockDim.x;
    for (; i < n; i += stride) dst[i] = __float2bfloat16(src[i]);
}

__global__ void init_h_k(const float* __restrict__ h0, __hip_bfloat16* __restrict__ hb) {
    int i = blockIdx.x * blockDim.x + threadIdx.x;
    if (i < BATCH * H) hb[i] = __float2bfloat16(h0[i]);
}

// ---------------- persistent LSTM: all 512 steps in one cooperative kernel ----
// 128 blocks x 512 threads (8 waves). Block owns 8 hidden cols (all 4 gates):
// 32 rows of [W_ih | W_hh] (K=1536) LDS-resident for the whole sequence.
// wave: wtile = wave&3 (16-batch-row M-tile), kh = wave>>2 (K-half of 768).
// One grid sync per step; h double-buffered in global.

__global__ __launch_bounds__(512, 1)
void lstm_persist(const __hip_bfloat16* __restrict__ xb,   // [SEQ][B][INF] bf16
                  const __hip_bfloat16* __restrict__ Wih,  // [4096][512]  bf16
                  const __hip_bfloat16* __restrict__ Whh,  // [4096][1024] bf16
                  const float* __restrict__ bias,          // [4096] f32
                  const float* __restrict__ c0,            // [B][H] f32
                  __hip_bfloat16* __restrict__ hbuf,       // [2][B][H] bf16 (buf0 = h0)
                  float* __restrict__ out)                 // h_seq | hT | cT
{
    __shared__ __align__(16) __hip_bfloat16 Wc[WROWS * WPITCH]; // 98,816 B
    __shared__ float Gs[2][BATCH][33];                          // 16,896 B (K-half partials)

    const int tid   = threadIdx.x;
    const int lane  = tid & 63;
    const int wave  = tid >> 6;       // 0..7
    const int wtile = wave & 3;       // batch m-tile (16 rows)
    const int kh    = wave >> 2;      // K-half
    const int ln15  = lane & 15;
    const int kgrp  = lane >> 4;      // 0..3
    const int j0    = blockIdx.x * NCOL;

    // ---- prologue: stage combined weight rows [Wih(512) | Whh(1024)] ----
    // row r = g*8 + jj  ->  global gate row g*H + j0 + jj
    for (int u = tid; u < WROWS * 192; u += 512) {   // 192 short8 per row
        int r    = u / 192;
        int seg  = u - r * 192;                      // 0..191 (16B units)
        int grow = (r >> 3) * H + j0 + (r & 7);
        if (seg < 64) {
            short8 v = *(const short8*)(Wih + (size_t)grow * INF + seg * 8);
            *(short8*)&Wc[r * WPITCH + seg * 8] = v;
        } else {
            short8 v = *(const short8*)(Whh + (size_t)grow * H + (seg - 64) * 8);
            *(short8*)&Wc[r * WPITCH + 512 + (seg - 64) * 8] = v;
        }
    }
    // per-thread elementwise ownership: one (b, j) pair
    const int eb = tid >> 3;          // batch 0..63
    const int ej = tid & 7;           // col   0..7
    const int cidx = eb * H + j0 + ej;
    float c_reg = c0[cidx];
    float bias_r[4];
    #pragma unroll
    for (int g = 0; g < 4; ++g) bias_r[g] = bias[g * H + j0 + ej];
    __syncthreads();

    cg::grid_group grid = cg::this_grid();

    const int arow = wtile * 16 + ln15;    // A-operand batch row for this lane
    float last_h = 0.f;

    for (int t = 0; t < SEQ; ++t) {
        const __hip_bfloat16* hp = hbuf + (size_t)(t & 1) * (BATCH * H);
        const __hip_bfloat16* xrow = xb + ((size_t)t * BATCH + arow) * INF + kgrp * 8;
        const __hip_bfloat16* hrow = hp + (size_t)arow * H + kgrp * 8;
        const __hip_bfloat16* wrow0 = &Wc[ln15 * WPITCH + kgrp * 8];
        const __hip_bfloat16* wrow1 = &Wc[(16 + ln15) * WPITCH + kgrp * 8];

        float4v acc0 = {0.f, 0.f, 0.f, 0.f};
        float4v acc1 = {0.f, 0.f, 0.f, 0.f};

        if (kh == 0) {
            // x part: global k 0..511
            #pragma unroll 8
            for (int ks = 0; ks < 16; ++ks) {
                short8 af = *(const short8*)(xrow + ks * 32);
                short8 b0 = *(const short8*)(wrow0 + ks * 32);
                short8 b1 = *(const short8*)(wrow1 + ks * 32);
                acc0 = __builtin_amdgcn_mfma_f32_16x16x32_bf16(af, b0, acc0, 0, 0, 0);
                acc1 = __builtin_amdgcn_mfma_f32_16x16x32_bf16(af, b1, acc1, 0, 0, 0);
            }
            // h part: h-k 0..255  (combined k 512..767)
            #pragma unroll 8
            for (int ks = 0; ks < 8; ++ks) {
                short8 af = *(const short8*)(hrow + ks * 32);
                short8 b0 = *(const short8*)(wrow0 + 512 + ks * 32);
                short8 b1 = *(const short8*)(wrow1 + 512 + ks * 32);
                acc0 = __builtin_amdgcn_mfma_f32_16x16x32_bf16(af, b0, acc0, 0, 0, 0);
                acc1 = __builtin_amdgcn_mfma_f32_16x16x32_bf16(af, b1, acc1, 0, 0, 0);
            }
        } else {
            // h part: h-k 256..1023 (combined k 768..1535)
            #pragma unroll 8
            for (int ks = 8; ks < 32; ++ks) {
                short8 af = *(const short8*)(hrow + ks * 32);
                short8 b0 = *(const short8*)(wrow0 + 512 + ks * 32);
                short8 b1 = *(const short8*)(wrow1 + 512 + ks * 32);
                acc0 = __builtin_amdgcn_mfma_f32_16x16x32_bf16(af, b0, acc0, 0, 0, 0);
                acc1 = __builtin_amdgcn_mfma_f32_16x16x32_bf16(af, b1, acc1, 0, 0, 0);
            }
        }

        // C/D layout: col = lane&15 (weight row n), row = kgrp*4 + r (batch)
        #pragma unroll
        for (int r = 0; r < 4; ++r) {
            int brow = wtile * 16 + kgrp * 4 + r;
            Gs[kh][brow][ln15]      = acc0[r];
            Gs[kh][brow][16 + ln15] = acc1[r];
        }
        __syncthreads();

        // elementwise: 512 threads, one (b, j) each. n = g*8 + jj
        float xi = Gs[0][eb][0 * 8 + ej] + Gs[1][eb][0 * 8 + ej] + bias_r[0];
        float xf = Gs[0][eb][1 * 8 + ej] + Gs[1][eb][1 * 8 + ej] + bias_r[1];
        float xg = Gs[0][eb][2 * 8 + ej] + Gs[1][eb][2 * 8 + ej] + bias_r[2];
        float xo = Gs[0][eb][3 * 8 + ej] + Gs[1][eb][3 * 8 + ej] + bias_r[3];
        float ig = 1.f / (1.f + __expf(-xi));
        float fg = 1.f / (1.f + __expf(-xf));
        float gg = 2.f / (1.f + __expf(-2.f * xg)) - 1.f;
        float og = 1.f / (1.f + __expf(-xo));
        c_reg = fg * c_reg + ig * gg;
        float th = 2.f / (1.f + __expf(-2.f * c_reg)) - 1.f;
        float h  = og * th;
        last_h   = h;
        out[(size_t)t * (BATCH * H) + cidx] = h;
        hbuf[(size_t)((t + 1) & 1) * (BATCH * H) + cidx] = __float2bfloat16(h);

        grid.sync();   // h(t+1) visible everywhere; also block-level barrier for Gs reuse
    }

    // tail: hT, cT
    out[(size_t)SEQ * BATCH * H + cidx]             = last_h;
    out[(size_t)SEQ * BATCH * H + BATCH * H + cidx] = c_reg;
}

// ---------------- launch ----------------

extern "C" void kernel_launch(void* const* d_in, const int* in_sizes, int n_in,
                              void* d_out, int out_size, void* d_ws, size_t ws_size,
                              hipStream_t stream)
{
    const float* x    = (const float*)d_in[0];
    const float* Wih  = (const float*)d_in[1];
    const float* Whh  = (const float*)d_in[2];
    const float* bias = (const float*)d_in[3];
    const float* h0   = (const float*)d_in[4];
    const float* c0   = (const float*)d_in[5];
    float* out = (float*)d_out;

    // workspace layout (bytes), 16B-aligned; total 46,399,488 B
    char* ws = (char*)d_ws;
    __hip_bfloat16* xb   = (__hip_bfloat16*)(ws);             // 33,554,432 B
    __hip_bfloat16* Wihb = (__hip_bfloat16*)(ws + 33554432);  //  4,194,304 B
    __hip_bfloat16* Whhb = (__hip_bfloat16*)(ws + 37748736);  //  8,388,608 B
    __hip_bfloat16* hb   = (__hip_bfloat16*)(ws + 46137344);  //    262,144 B (2 x B x H)

    f32_to_bf16_k<<<2048, 256, 0, stream>>>(x,   xb,   SEQ * BATCH * INF);
    f32_to_bf16_k<<<512,  256, 0, stream>>>(Wih, Wihb, G4H * INF);
    f32_to_bf16_k<<<1024, 256, 0, stream>>>(Whh, Whhb, G4H * H);
    init_h_k<<<256, 256, 0, stream>>>(h0, hb);

    void* kargs[] = { (void*)&xb, (void*)&Wihb, (void*)&Whhb,
                      (void*)&bias, (void*)&c0, (void*)&hb, (void*)&out };
    hipLaunchCooperativeKernel((void*)lstm_persist, dim3(NBLK), dim3(512),
                               kargs, 0, stream);
}

// Round 2
// 7735.682 us; speedup vs baseline: 1.4664x; 1.4664x over previous
//
#include <hip/hip_runtime.h>
#include <hip/hip_bf16.h>

#define SEQ   512
#define BATCH 64
#define INF   512
#define H     1024
#define G4H   4096

#define NBLK   128          // persistent blocks, 1/CU (LDS-bound), co-resident via coop launch
#define NCOL   8            // hidden columns per block
#define WROWS  32           // 4 gates * NCOL weight rows per block
#define WPITCH 1544         // 1536 + 8 bf16 pad (rows 16B-aligned)

typedef short  short8  __attribute__((ext_vector_type(8)));
typedef float  float4v __attribute__((ext_vector_type(4)));

// ---------------- conversion / init kernels ----------------

__global__ void f32_to_bf16_k(const float* __restrict__ src,
                              __hip_bfloat16* __restrict__ dst, int n) {
    int i = blockIdx.x * blockDim.x + threadIdx.x;
    int stride = gridDim.x * blockDim.x;
    for (; i < n; i += stride) dst[i] = __float2bfloat16(src[i]);
}

__global__ void init_h_k(const float* __restrict__ h0, __hip_bfloat16* __restrict__ hb,
                         int* __restrict__ cnt) {
    int i = blockIdx.x * blockDim.x + threadIdx.x;
    if (i < BATCH * H) hb[i] = __float2bfloat16(h0[i]);
    if (i == 0) *cnt = 0;
}

// ---------------- persistent LSTM: all 512 steps, one kernel, custom barrier ----
// 128 blocks x 512 threads (8 waves). Block owns 8 hidden cols (all 4 gates):
// 32 rows of [W_ih | W_hh] (K=1536) LDS-resident for the whole sequence.
// Wave split: wm = wave&3 (16-row batch M-tile), wn = wave>>2 (16-col N-half).
// Each wave: one 16x16 output tile, full K=1536 (x-part pre-barrier, h-part post).
// Barrier: monotonic counter, tid0 arrives (release) / spins (relaxed + acquire).

__global__ __launch_bounds__(512, 1)
void lstm_persist(const __hip_bfloat16* __restrict__ xb,   // [SEQ][B][INF] bf16
                  const __hip_bfloat16* __restrict__ Wih,  // [4096][512]  bf16
                  const __hip_bfloat16* __restrict__ Whh,  // [4096][1024] bf16
                  const float* __restrict__ bias,          // [4096] f32
                  const float* __restrict__ c0,            // [B][H] f32
                  __hip_bfloat16* __restrict__ hbuf,       // [2][B][H] bf16 (buf0 = h0)
                  int* __restrict__ cnt,                   // barrier counter (init 0)
                  float* __restrict__ out)                 // h_seq | hT | cT
{
    __shared__ __align__(16) __hip_bfloat16 Wc[WROWS * WPITCH]; // 98,816 B
    __shared__ float Gs[BATCH][33];                             //  8,448 B

    const int tid   = threadIdx.x;
    const int lane  = tid & 63;
    const int wave  = tid >> 6;       // 0..7
    const int wm    = wave & 3;       // batch m-tile (16 rows)
    const int wn    = wave >> 2;      // N-half (16 of 32 gate rows)
    const int ln15  = lane & 15;
    const int kgrp  = lane >> 4;      // 0..3
    const int j0    = blockIdx.x * NCOL;

    // ---- prologue: stage combined weight rows [Wih(512) | Whh(1024)] ----
    // Wc row r = g*8 + jj  <->  global gate row g*H + j0 + jj
    for (int u = tid; u < WROWS * 192; u += 512) {   // 192 short8 per row
        int r    = u / 192;
        int seg  = u - r * 192;                      // 0..191 (16B units)
        int grow = (r >> 3) * H + j0 + (r & 7);
        if (seg < 64) {
            short8 v = *(const short8*)(Wih + (size_t)grow * INF + seg * 8);
            *(short8*)&Wc[r * WPITCH + seg * 8] = v;
        } else {
            short8 v = *(const short8*)(Whh + (size_t)grow * H + (seg - 64) * 8);
            *(short8*)&Wc[r * WPITCH + 512 + (seg - 64) * 8] = v;
        }
    }
    // per-thread elementwise ownership: one (b, j) pair
    const int eb   = tid >> 3;        // batch 0..63
    const int ej   = tid & 7;         // col   0..7
    const int cidx = eb * H + j0 + ej;
    float c_reg = c0[cidx];
    float bias_r[4];
    #pragma unroll
    for (int g = 0; g < 4; ++g) bias_r[g] = bias[g * H + j0 + ej];
    __syncthreads();

    const int arow = wm * 16 + ln15;                 // A-operand batch row
    const __hip_bfloat16* wbase = &Wc[(wn * 16 + ln15) * WPITCH + kgrp * 8];
    float last_h = 0.f;

    for (int t = 0; t < SEQ; ++t) {
        // ---- A. x-part: no h dependence, runs while others still finish t-1 ----
        const __hip_bfloat16* xrow = xb + ((size_t)t * BATCH + arow) * INF + kgrp * 8;
        float4v acc0 = {0.f, 0.f, 0.f, 0.f};
        float4v acc1 = {0.f, 0.f, 0.f, 0.f};
        #pragma unroll
        for (int ks = 0; ks < 16; ks += 2) {
            short8 af0 = *(const short8*)(xrow + ks * 32);
            short8 bf0 = *(const short8*)(wbase + ks * 32);
            acc0 = __builtin_amdgcn_mfma_f32_16x16x32_bf16(af0, bf0, acc0, 0, 0, 0);
            short8 af1 = *(const short8*)(xrow + (ks + 1) * 32);
            short8 bf1 = *(const short8*)(wbase + (ks + 1) * 32);
            acc1 = __builtin_amdgcn_mfma_f32_16x16x32_bf16(af1, bf1, acc1, 0, 0, 0);
        }

        // ---- B. wait for h(t): all NBLK blocks arrived for step t-1 ----
        if (t > 0 && tid == 0) {
            const int target = NBLK * t;
            while (__hip_atomic_load(cnt, __ATOMIC_RELAXED, __HIP_MEMORY_SCOPE_AGENT) < target)
                __builtin_amdgcn_s_sleep(2);
            __threadfence();   // acquire: invalidate stale h in local caches
        }
        __syncthreads();

        // ---- C. h-part ----
        const __hip_bfloat16* hrow =
            hbuf + (size_t)(t & 1) * (BATCH * H) + (size_t)arow * H + kgrp * 8;
        #pragma unroll
        for (int ks = 0; ks < 32; ks += 2) {
            short8 af0 = *(const short8*)(hrow + ks * 32);
            short8 bf0 = *(const short8*)(wbase + 512 + ks * 32);
            acc0 = __builtin_amdgcn_mfma_f32_16x16x32_bf16(af0, bf0, acc0, 0, 0, 0);
            short8 af1 = *(const short8*)(hrow + (ks + 1) * 32);
            short8 bf1 = *(const short8*)(wbase + 512 + (ks + 1) * 32);
            acc1 = __builtin_amdgcn_mfma_f32_16x16x32_bf16(af1, bf1, acc1, 0, 0, 0);
        }

        // ---- D. gate exchange. C/D layout: col = lane&15 (n), row = kgrp*4+r (m) ----
        #pragma unroll
        for (int r = 0; r < 4; ++r)
            Gs[wm * 16 + kgrp * 4 + r][wn * 16 + ln15] = acc0[r] + acc1[r];
        __syncthreads();

        // ---- F. elementwise cell update: one (b, j) per thread ----
        float xi = Gs[eb][0 * 8 + ej] + bias_r[0];
        float xf = Gs[eb][1 * 8 + ej] + bias_r[1];
        float xg = Gs[eb][2 * 8 + ej] + bias_r[2];
        float xo = Gs[eb][3 * 8 + ej] + bias_r[3];
        float ig = 1.f / (1.f + __expf(-xi));
        float fg = 1.f / (1.f + __expf(-xf));
        float gg = 2.f / (1.f + __expf(-2.f * xg)) - 1.f;
        float og = 1.f / (1.f + __expf(-xo));
        c_reg = fg * c_reg + ig * gg;
        float th = 2.f / (1.f + __expf(-2.f * c_reg)) - 1.f;
        float h  = og * th;
        last_h   = h;
        out[(size_t)t * (BATCH * H) + cidx] = h;
        hbuf[(size_t)((t + 1) & 1) * (BATCH * H) + cidx] = __float2bfloat16(h);
        __syncthreads();   // all h(t+1) stores of this block complete (vmcnt drained)

        // ---- H. arrive: publish h(t+1) ----
        if (tid == 0) {
            __threadfence();   // release: write back dirty L2 (h slice) to coherent point
            __hip_atomic_fetch_add(cnt, 1, __ATOMIC_RELAXED, __HIP_MEMORY_SCOPE_AGENT);
        }
    }

    // tail: hT, cT
    out[(size_t)SEQ * BATCH * H + cidx]             = last_h;
    out[(size_t)SEQ * BATCH * H + BATCH * H + cidx] = c_reg;
}

// ---------------- launch ----------------

extern "C" void kernel_launch(void* const* d_in, const int* in_sizes, int n_in,
                              void* d_out, int out_size, void* d_ws, size_t ws_size,
                              hipStream_t stream)
{
    const float* x    = (const float*)d_in[0];
    const float* Wih  = (const float*)d_in[1];
    const float* Whh  = (const float*)d_in[2];
    const float* bias = (const float*)d_in[3];
    const float* h0   = (const float*)d_in[4];
    const float* c0   = (const float*)d_in[5];
    float* out = (float*)d_out;

    // workspace layout (bytes), 16B-aligned
    char* ws = (char*)d_ws;
    __hip_bfloat16* xb   = (__hip_bfloat16*)(ws);             // 33,554,432 B
    __hip_bfloat16* Wihb = (__hip_bfloat16*)(ws + 33554432);  //  4,194,304 B
    __hip_bfloat16* Whhb = (__hip_bfloat16*)(ws + 37748736);  //  8,388,608 B
    __hip_bfloat16* hb   = (__hip_bfloat16*)(ws + 46137344);  //    262,144 B (2 x B x H)
    int*            cnt  = (int*)(ws + 46399488);             //          4 B

    f32_to_bf16_k<<<2048, 256, 0, stream>>>(x,   xb,   SEQ * BATCH * INF);
    f32_to_bf16_k<<<512,  256, 0, stream>>>(Wih, Wihb, G4H * INF);
    f32_to_bf16_k<<<1024, 256, 0, stream>>>(Whh, Whhb, G4H * H);
    init_h_k<<<256, 256, 0, stream>>>(h0, hb, cnt);

    void* kargs[] = { (void*)&xb, (void*)&Wihb, (void*)&Whhb,
                      (void*)&bias, (void*)&c0, (void*)&hb, (void*)&cnt, (void*)&out };
    hipLaunchCooperativeKernel((void*)lstm_persist, dim3(NBLK), dim3(512),
                               kargs, 0, stream);
}